// Round 13
// baseline (143.483 us; speedup 1.0000x reference)
//
#include <hip/hip_runtime.h>
#include <math.h>

#define QN  4
#define CN  256
#define BN  32
#define NN  4096
#define WV  4            // waves per block
#define RPW 32           // rows per wave
#define SPB 32           // blocks per batch (NN/(WV*RPW))

// Issue 4 row-loads for the next compacted tile into dst[] (UNCONDITIONAL:
// exhausted slots reload row 0 so the waitcnt scoreboard stays static);
// validity nibble in vmdst gates their contribution later.
#define EXTRACT_ISSUE(dst, vmdst) do {                                   \
    vmdst = 0u;                                                          \
    _Pragma("unroll")                                                    \
    for (int j_ = 0; j_ < 4; ++j_) {                                     \
        const int r_ = um ? (int)__builtin_ctz(um) : 0;                  \
        if (um) vmdst |= (1u << j_);                                     \
        um &= um - 1u;                                                   \
        dst[j_] = *(const float4*)(hb + (size_t)r_ * CN);                \
    }                                                                    \
} while (0)

// Compute one 4-row tile from buffer bf with validity nibble vm:
// 16 dot partials -> reduce-scatter butterfly -> 1 exp -> readlane pool.
#define COMPUTE(bf, vm) do {                                             \
    float cur[16];                                                       \
    _Pragma("unroll")                                                    \
    for (int r_ = 0; r_ < 4; ++r_)                                       \
        _Pragma("unroll")                                                \
        for (int q_ = 0; q_ < QN; ++q_)                                  \
            cur[r_ * 4 + q_] = bf[r_].x * q4[q_].x + bf[r_].y * q4[q_].y \
                             + bf[r_].z * q4[q_].z + bf[r_].w * q4[q_].w;\
    _Pragma("unroll")                                                    \
    for (int k_ = 0; k_ < 4; ++k_) {                                     \
        const int  nv_ = 8 >> k_;                                        \
        const bool bk_ = (lane >> k_) & 1;                               \
        _Pragma("unroll")                                                \
        for (int j_ = 0; j_ < nv_; ++j_) {                               \
            const float snd_ = bk_ ? cur[2 * j_] : cur[2 * j_ + 1];      \
            const float rcv_ = __shfl_xor(snd_, 1 << k_, 64);            \
            cur[j_] = (bk_ ? cur[2 * j_ + 1] : cur[2 * j_]) + rcv_;      \
        }                                                                \
    }                                                                    \
    float sv_ = cur[0];                                                  \
    sv_ += __shfl_xor(sv_, 16, 64);                                      \
    sv_ += __shfl_xor(sv_, 32, 64);                                      \
    const bool  ok_ = ((vm) >> rheld) & 1u;                              \
    const float pv_ = ok_ ? __expf(sv_) : 0.f;                           \
    lheld += pv_;                                                        \
    _Pragma("unroll")                                                    \
    for (int r_ = 0; r_ < 4; ++r_)                                       \
        _Pragma("unroll")                                                \
        for (int q_ = 0; q_ < QN; ++q_) {                                \
            const float prq_ = __uint_as_float(__builtin_amdgcn_readlane(\
                __float_as_uint(pv_), r_ * 4 + q_));                     \
            acc[q_].x += prq_ * bf[r_].x;                                \
            acc[q_].y += prq_ * bf[r_].y;                                \
            acc[q_].z += prq_ * bf[r_].z;                                \
            acc[q_].w += prq_ * bf[r_].w;                                \
        }                                                                \
} while (0)

// ---------------------------------------------------------------------------
// Fused single-launch (no-max softmax: |s| <= ~16, fp32 headroom huge).
// Main loop identical to round-11 (validated fastest, DRAM-page-bound):
// compacted unmasked rows, 4-row tiles, modulo-3 register pipeline.
// Finish: per-batch counter (memset-zeroed each call); TRUE last block
// (old == SPB-1; R9's bug was firing at (old&31)==31 from a poisoned
// counter) reduces the 32 partials (L3-warm) and divides.  Standard
// decoupled protocol: threadfence -> ACQ_REL fetch_add -> acquire reads.
// grid = BN*SPB = 1024 blocks x 256 threads.
// ---------------------------------------------------------------------------
__global__ __launch_bounds__(256) void k_fused(
    const float* __restrict__ h, const int* __restrict__ mask,
    const float* __restrict__ qr,
    float* __restrict__ P, float* __restrict__ Lp,
    unsigned int* __restrict__ cnt, float* __restrict__ out)
{
    __shared__ float s_part[WV][QN * CN];   // 16 KB, epilogue only
    __shared__ float s_lp[WV][QN];
    __shared__ int   s_last;

    const int b    = blockIdx.x >> 5;
    const int sub  = blockIdx.x & (SPB - 1);
    const int w    = threadIdx.x >> 6;
    const int lane = threadIdx.x & 63;

    const int n0    = (sub * WV + w) * RPW;
    const size_t gn = (size_t)b * NN + n0;
    const float* __restrict__ hb = h + gn * CN + lane * 4;

    // lane's 4 channels of each query (scale folded in): 16 VGPRs
    float4 q4[QN];
#pragma unroll
    for (int q = 0; q < QN; ++q) {
        float4 tq = *(const float4*)(qr + q * CN + lane * 4);
        tq.x *= 0.0625f; tq.y *= 0.0625f; tq.z *= 0.0625f; tq.w *= 0.0625f;
        q4[q] = tq;
    }

    // unmasked-row bitmap for this wave's 32 rows (wave-uniform scalar)
    const unsigned long long mbits =
        __ballot(lane < RPW ? (mask[gn + lane] != 0) : true);
    unsigned um = (unsigned)(~mbits & 0xFFFFFFFFull);
    const int K   = __popc(um);
    const int NTv = (K + 3) >> 2;         // tiles of 4 compacted rows

    float4 acc[QN];
#pragma unroll
    for (int q = 0; q < QN; ++q) acc[q] = make_float4(0.f, 0.f, 0.f, 0.f);

    float lheld = 0.f;                    // p-sum for this lane's held (r,q)
    const int rheld = (lane >> 2) & 3;    // slot whose sum this lane holds

    float4 va[4], vb[4], vz[4];
    unsigned vmA, vmB, vmZ;

    if (NTv > 0) {
        // prologue: tiles 0 and 1
        EXTRACT_ISSUE(va, vmA);
        EXTRACT_ISSUE(vb, vmB);

        int t = 0;
        while (true) {
            EXTRACT_ISSUE(vz, vmZ);       // tile t+2
            COMPUTE(va, vmA);             // tile t
            if (++t >= NTv) break;

            EXTRACT_ISSUE(va, vmA);       // tile t+2
            COMPUTE(vb, vmB);             // tile t+1
            if (++t >= NTv) break;

            EXTRACT_ISSUE(vb, vmB);       // tile t+2
            COMPUTE(vz, vmZ);             // tile t+2 of prev group
            if (++t >= NTv) break;
        }
    }

    // ---- l[q]: fold slots (lane bits 2,3); lanes 0..3 hold q=lane ----
    float lt = lheld;
    lt += __shfl_xor(lt, 4, 64);
    lt += __shfl_xor(lt, 8, 64);

    // ---- block combine via LDS; write per-block partial ----
#pragma unroll
    for (int q = 0; q < QN; ++q)
        *(float4*)&s_part[w][q * CN + lane * 4] = acc[q];
    if (lane < QN) s_lp[w][lane] = lt;
    __syncthreads();
    {
        const int tt = threadIdx.x;              // 256 threads x float4
        float4 o = make_float4(0.f, 0.f, 0.f, 0.f);
#pragma unroll
        for (int ww = 0; ww < WV; ++ww) {
            const float4 v = *(const float4*)&s_part[ww][tt * 4];
            o.x += v.x; o.y += v.y; o.z += v.z; o.w += v.w;
        }
        ((float4*)(P + (size_t)blockIdx.x * (QN * CN)))[tt] = o;
        if (tt < QN)
            Lp[blockIdx.x * QN + tt] =
                s_lp[0][tt] + s_lp[1][tt] + s_lp[2][tt] + s_lp[3][tt];
    }

    // ---- decoupled finish: true last block of this batch reduces ----
    __threadfence();                      // make this thread's stores visible
    __syncthreads();
    if (threadIdx.x == 0) {
        const unsigned int old = __hip_atomic_fetch_add(
            &cnt[b], 1u, __ATOMIC_ACQ_REL, __HIP_MEMORY_SCOPE_AGENT);
        s_last = (old == (unsigned)(SPB - 1)) ? 1 : 0;
    }
    __syncthreads();

    if (s_last) {
        __threadfence();                  // acquire for each reader thread
        const int tt = threadIdx.x;
        const int q  = tt >> 6;
        const size_t pbase = (size_t)b * SPB * (QN * CN);

        float l = 0.f;
#pragma unroll
        for (int s = 0; s < SPB; ++s)
            l += __hip_atomic_load(&Lp[(b * SPB + s) * QN + q],
                                   __ATOMIC_RELAXED, __HIP_MEMORY_SCOPE_AGENT);

        float o0 = 0.f, o1 = 0.f, o2 = 0.f, o3 = 0.f;
#pragma unroll
        for (int s = 0; s < SPB; ++s) {
            const float* ps = P + pbase + (size_t)s * (QN * CN) + tt * 4;
            o0 += __hip_atomic_load(ps + 0, __ATOMIC_RELAXED,
                                    __HIP_MEMORY_SCOPE_AGENT);
            o1 += __hip_atomic_load(ps + 1, __ATOMIC_RELAXED,
                                    __HIP_MEMORY_SCOPE_AGENT);
            o2 += __hip_atomic_load(ps + 2, __ATOMIC_RELAXED,
                                    __HIP_MEMORY_SCOPE_AGENT);
            o3 += __hip_atomic_load(ps + 3, __ATOMIC_RELAXED,
                                    __HIP_MEMORY_SCOPE_AGENT);
        }
        const float inv = (l > 0.f) ? 1.f / l : 0.f;
        float4 ov;
        ov.x = o0 * inv; ov.y = o1 * inv; ov.z = o2 * inv; ov.w = o3 * inv;
        *(float4*)(out + (size_t)b * (QN * CN) + tt * 4) = ov;
    }
}

extern "C" void kernel_launch(void* const* d_in, const int* in_sizes, int n_in,
                              void* d_out, int out_size, void* d_ws, size_t ws_size,
                              hipStream_t stream) {
    const float* h    = (const float*)d_in[0];
    const int*   mask = (const int*)d_in[1];
    const float* qr   = (const float*)d_in[2];
    float*       out  = (float*)d_out;

    float*        P   = (float*)d_ws;                    // [1024][Q*C] = 4 MB
    float*        Lp  = P + (size_t)BN * SPB * QN * CN;  // [1024][Q]   = 16 KB
    unsigned int* cnt = (unsigned int*)(Lp + (size_t)BN * SPB * QN);  // [32]

    hipMemsetAsync(cnt, 0, BN * sizeof(unsigned int), stream);
    k_fused<<<BN * SPB, 256, 0, stream>>>(h, mask, qr, P, Lp, cnt, out);
}

// Round 14
// 23.647 us; speedup vs baseline: 6.0676x; 6.0676x over previous
//
#include <hip/hip_runtime.h>
#include <math.h>

#define QN  4
#define CN  256
#define BN  32
#define NN  4096
#define WV  4            // waves per block
#define RPW 32           // rows per wave
#define SPB 32           // blocks per batch (NN/(WV*RPW))

// Issue 4 row-loads for the next compacted tile into dst[] (UNCONDITIONAL:
// exhausted slots reload row 0 so the waitcnt scoreboard stays static);
// validity nibble in vmdst gates their contribution later.
#define EXTRACT_ISSUE(dst, vmdst) do {                                   \
    vmdst = 0u;                                                          \
    _Pragma("unroll")                                                    \
    for (int j_ = 0; j_ < 4; ++j_) {                                     \
        const int r_ = um ? (int)__builtin_ctz(um) : 0;                  \
        if (um) vmdst |= (1u << j_);                                     \
        um &= um - 1u;                                                   \
        dst[j_] = *(const float4*)(hb + (size_t)r_ * CN);                \
    }                                                                    \
} while (0)

// Compute one 4-row tile from buffer bf with validity nibble vm:
// 16 dot partials -> reduce-scatter butterfly -> 1 exp -> readlane pool.
#define COMPUTE(bf, vm) do {                                             \
    float cur[16];                                                       \
    _Pragma("unroll")                                                    \
    for (int r_ = 0; r_ < 4; ++r_)                                       \
        _Pragma("unroll")                                                \
        for (int q_ = 0; q_ < QN; ++q_)                                  \
            cur[r_ * 4 + q_] = bf[r_].x * q4[q_].x + bf[r_].y * q4[q_].y \
                             + bf[r_].z * q4[q_].z + bf[r_].w * q4[q_].w;\
    _Pragma("unroll")                                                    \
    for (int k_ = 0; k_ < 4; ++k_) {                                     \
        const int  nv_ = 8 >> k_;                                        \
        const bool bk_ = (lane >> k_) & 1;                               \
        _Pragma("unroll")                                                \
        for (int j_ = 0; j_ < nv_; ++j_) {                               \
            const float snd_ = bk_ ? cur[2 * j_] : cur[2 * j_ + 1];      \
            const float rcv_ = __shfl_xor(snd_, 1 << k_, 64);            \
            cur[j_] = (bk_ ? cur[2 * j_ + 1] : cur[2 * j_]) + rcv_;      \
        }                                                                \
    }                                                                    \
    float sv_ = cur[0];                                                  \
    sv_ += __shfl_xor(sv_, 16, 64);                                      \
    sv_ += __shfl_xor(sv_, 32, 64);                                      \
    const bool  ok_ = ((vm) >> rheld) & 1u;                              \
    const float pv_ = ok_ ? __expf(sv_) : 0.f;                           \
    lheld += pv_;                                                        \
    _Pragma("unroll")                                                    \
    for (int r_ = 0; r_ < 4; ++r_)                                       \
        _Pragma("unroll")                                                \
        for (int q_ = 0; q_ < QN; ++q_) {                                \
            const float prq_ = __uint_as_float(__builtin_amdgcn_readlane(\
                __float_as_uint(pv_), r_ * 4 + q_));                     \
            acc[q_].x += prq_ * bf[r_].x;                                \
            acc[q_].y += prq_ * bf[r_].y;                                \
            acc[q_].z += prq_ * bf[r_].z;                                \
            acc[q_].w += prq_ * bf[r_].w;                                \
        }                                                                \
} while (0)

// ---------------------------------------------------------------------------
// Fused single-pass (no-max softmax: |s| <= ~16, fp32 headroom huge).
// Round-11 kernel VERBATIM (validated 4x, DRAM-page-bound at ~21 us):
// compacted unmasked rows, 4-row tiles, modulo-3 register pipeline with
// role-rotating buffers (no copies -> SSA renaming -> counted vmcnt waits).
// NOTE: do NOT append a finish phase here — R13 showed it re-costs the
// register allocation (VGPR 116->60) and destroys the load pipeline (6x).
// grid = BN*SPB = 1024 blocks x 256 thr; 16 KB LDS -> 4 wv/SIMD.
// ---------------------------------------------------------------------------
__global__ __launch_bounds__(256) void k_fused(
    const float* __restrict__ h, const int* __restrict__ mask,
    const float* __restrict__ qr,
    float* __restrict__ P, float* __restrict__ Lp)
{
    __shared__ float s_part[WV][QN * CN];   // 16 KB, epilogue only
    __shared__ float s_lp[WV][QN];

    const int b    = blockIdx.x >> 5;
    const int sub  = blockIdx.x & (SPB - 1);
    const int w    = threadIdx.x >> 6;
    const int lane = threadIdx.x & 63;

    const int n0    = (sub * WV + w) * RPW;
    const size_t gn = (size_t)b * NN + n0;
    const float* __restrict__ hb = h + gn * CN + lane * 4;

    // lane's 4 channels of each query (scale folded in): 16 VGPRs
    float4 q4[QN];
#pragma unroll
    for (int q = 0; q < QN; ++q) {
        float4 tq = *(const float4*)(qr + q * CN + lane * 4);
        tq.x *= 0.0625f; tq.y *= 0.0625f; tq.z *= 0.0625f; tq.w *= 0.0625f;
        q4[q] = tq;
    }

    // unmasked-row bitmap for this wave's 32 rows (wave-uniform scalar)
    const unsigned long long mbits =
        __ballot(lane < RPW ? (mask[gn + lane] != 0) : true);
    unsigned um = (unsigned)(~mbits & 0xFFFFFFFFull);
    const int K   = __popc(um);
    const int NTv = (K + 3) >> 2;         // tiles of 4 compacted rows

    float4 acc[QN];
#pragma unroll
    for (int q = 0; q < QN; ++q) acc[q] = make_float4(0.f, 0.f, 0.f, 0.f);

    float lheld = 0.f;                    // p-sum for this lane's held (r,q)
    const int rheld = (lane >> 2) & 3;    // slot whose sum this lane holds

    float4 va[4], vb[4], vz[4];
    unsigned vmA, vmB, vmZ;

    if (NTv > 0) {
        // prologue: tiles 0 and 1
        EXTRACT_ISSUE(va, vmA);
        EXTRACT_ISSUE(vb, vmB);

        int t = 0;
        while (true) {
            EXTRACT_ISSUE(vz, vmZ);       // tile t+2
            COMPUTE(va, vmA);             // tile t
            if (++t >= NTv) break;

            EXTRACT_ISSUE(va, vmA);       // tile t+2
            COMPUTE(vb, vmB);             // tile t+1
            if (++t >= NTv) break;

            EXTRACT_ISSUE(vb, vmB);       // tile t+2
            COMPUTE(vz, vmZ);             // tile t+2 of prev group
            if (++t >= NTv) break;
        }
    }

    // ---- l[q]: fold slots (lane bits 2,3); lanes 0..3 hold q=lane ----
    float lt = lheld;
    lt += __shfl_xor(lt, 4, 64);
    lt += __shfl_xor(lt, 8, 64);

    // ---- block combine via LDS; write per-block partial ----
#pragma unroll
    for (int q = 0; q < QN; ++q)
        *(float4*)&s_part[w][q * CN + lane * 4] = acc[q];
    if (lane < QN) s_lp[w][lane] = lt;
    __syncthreads();
    {
        const int tt = threadIdx.x;              // 256 threads x float4
        float4 o = make_float4(0.f, 0.f, 0.f, 0.f);
#pragma unroll
        for (int ww = 0; ww < WV; ++ww) {
            const float4 v = *(const float4*)&s_part[ww][tt * 4];
            o.x += v.x; o.y += v.y; o.z += v.z; o.w += v.w;
        }
        ((float4*)(P + (size_t)blockIdx.x * (QN * CN)))[tt] = o;
        if (tt < QN)
            Lp[blockIdx.x * QN + tt] =
                s_lp[0][tt] + s_lp[1][tt] + s_lp[2][tt] + s_lp[3][tt];
    }
}

// ---------------------------------------------------------------------------
// Combine SPB block-partials per batch and divide by l (0 if l==0).
// FULL unroll -> all 32 partial loads issued back-to-back (one latency
// round-trip instead of 8 serialized ones at unroll-4).
// grid = BN*QN blocks x 256 threads; q block-uniform (scalar Lp loads).
// ---------------------------------------------------------------------------
__global__ __launch_bounds__(256) void k_div(
    const float* __restrict__ P, const float* __restrict__ Lp,
    float* __restrict__ out)
{
    const int b   = blockIdx.x >> 2;
    const int q   = blockIdx.x & 3;
    const int idx = q * CN + threadIdx.x;

    float o = 0.f, l = 0.f;
#pragma unroll
    for (int s = 0; s < SPB; ++s) {
        o += P[(size_t)(b * SPB + s) * (QN * CN) + idx];
        l += Lp[(b * SPB + s) * QN + q];
    }
    out[(size_t)b * (QN * CN) + idx] = (l > 0.f) ? o / l : 0.f;
}

extern "C" void kernel_launch(void* const* d_in, const int* in_sizes, int n_in,
                              void* d_out, int out_size, void* d_ws, size_t ws_size,
                              hipStream_t stream) {
    const float* h    = (const float*)d_in[0];
    const int*   mask = (const int*)d_in[1];
    const float* qr   = (const float*)d_in[2];
    float*       out  = (float*)d_out;

    float* P  = (float*)d_ws;                           // [1024][Q*C] = 4 MB
    float* Lp = P + (size_t)BN * SPB * QN * CN;         // [1024][Q]   = 16 KB

    k_fused<<<BN * SPB, 256, 0, stream>>>(h, mask, qr, P, Lp);
    k_div  <<<BN * QN, 256, 0, stream>>>(P, Lp, out);
}